// Round 6
// baseline (272.242 us; speedup 1.0000x reference)
//
#include <hip/hip_runtime.h>
#include <hip/hip_bf16.h>

#define S_LEN 4096
#define DM    768
#define NH    12
#define DKH   64

typedef __attribute__((ext_vector_type(8))) short short8;
typedef __attribute__((ext_vector_type(4))) float f32x4;

__device__ __forceinline__ short f2bf(float f) {
    union { float f; unsigned u; } v; v.f = f;
    unsigned r = (v.u + 0x7FFFu + ((v.u >> 16) & 1u)) >> 16;
    return (short)r;
}

#define MFMA16(a, b, c) __builtin_amdgcn_mfma_f32_16x16x32_bf16((a), (b), (c), 0, 0, 0)

// ---------------------------------------------------------------- converts
__global__ __launch_bounds__(256) void to_bf16_k(const float* __restrict__ src,
                                                 short* __restrict__ dst, int n) {
    int i = (blockIdx.x * 256 + threadIdx.x) * 4;
    if (i >= n) return;
    float4 v = *reinterpret_cast<const float4*>(src + i);
    short4 o;
    o.x = f2bf(v.x); o.y = f2bf(v.y); o.z = f2bf(v.z); o.w = f2bf(v.w);
    *reinterpret_cast<short4*>(dst + i) = o;
}

__global__ __launch_bounds__(256) void rope_table_k(const int* __restrict__ pos,
                                                    float2* __restrict__ rt) {
    int idx = blockIdx.x * 256 + threadIdx.x;
    if (idx >= S_LEN * 32) return;
    int s = idx >> 5, i = idx & 31;
    int p = pos[s]; p = p < 0 ? 0 : (p > 4095 ? 4095 : p);
    double inv = pow(10000.0, -(double)i / 32.0);
    float ang = (float)((double)p * inv);
    rt[idx] = make_float2(cosf(ang), sinf(ang));
}

// ---------------------------------------------------------------- GEMM core
// m97 structure: 128x128 tile, BK=32, global_load_lds(16B) staging with
// XOR-chunk swizzle on the GLOBAL source (linear LDS dest, rule #21).
__device__ __forceinline__ void gemm_mainloop(const short* __restrict__ A,
                                              const short* __restrict__ B,
                                              short* Al, short* Bl,
                                              int m0, int n0, int t,
                                              f32x4 acc[4][4]) {
    const int wave = t >> 6, lane = t & 63;
    const int wm = (wave >> 1) * 64, wn = (wave & 1) * 64;
    const int l15 = lane & 15, lg = lane >> 4;
    const int srow = lane >> 2;
    const int gca = (lane & 3) ^ (srow & 3);
    const int c8a = lg ^ (l15 & 3);
    short* dstA0 = Al + (wave * 2 + 0) * 512 + lane * 8;
    short* dstA1 = Al + (wave * 2 + 1) * 512 + lane * 8;
    short* dstB0 = Bl + (wave * 2 + 0) * 512 + lane * 8;
    short* dstB1 = Bl + (wave * 2 + 1) * 512 + lane * 8;
    const int ra0 = (wave * 2 + 0) * 16 + srow;
    const int ra1 = (wave * 2 + 1) * 16 + srow;
    for (int k0 = 0; k0 < DM; k0 += 32) {
        __syncthreads();
        __builtin_amdgcn_global_load_lds(
            (const __attribute__((address_space(1))) void*)&A[(m0 + ra0) * DM + k0 + gca * 8],
            (__attribute__((address_space(3))) void*)dstA0, 16, 0, 0);
        __builtin_amdgcn_global_load_lds(
            (const __attribute__((address_space(1))) void*)&A[(m0 + ra1) * DM + k0 + gca * 8],
            (__attribute__((address_space(3))) void*)dstA1, 16, 0, 0);
        __builtin_amdgcn_global_load_lds(
            (const __attribute__((address_space(1))) void*)&B[(n0 + ra0) * DM + k0 + gca * 8],
            (__attribute__((address_space(3))) void*)dstB0, 16, 0, 0);
        __builtin_amdgcn_global_load_lds(
            (const __attribute__((address_space(1))) void*)&B[(n0 + ra1) * DM + k0 + gca * 8],
            (__attribute__((address_space(3))) void*)dstB1, 16, 0, 0);
        __syncthreads();
        short8 af[4], bf[4];
#pragma unroll
        for (int m = 0; m < 4; ++m)
            af[m] = *reinterpret_cast<const short8*>(Al + (wm + m * 16 + l15) * 32 + c8a * 8);
#pragma unroll
        for (int n = 0; n < 4; ++n)
            bf[n] = *reinterpret_cast<const short8*>(Bl + (wn + n * 16 + l15) * 32 + c8a * 8);
#pragma unroll
        for (int m = 0; m < 4; ++m)
#pragma unroll
            for (int n = 0; n < 4; ++n)
                acc[m][n] = MFMA16(af[m], bf[n], acc[m][n]);
    }
}

// QKV projection + fused RoPE (+ 1/8*log2e on Q) + fused V-transpose.
// grid = (6, 32, 3)
__global__ __launch_bounds__(256) void gemm_qkv_k(
    const short* __restrict__ Xbf, const short* __restrict__ Wq,
    const short* __restrict__ Wk, const short* __restrict__ Wv,
    const float2* __restrict__ rt,
    short* __restrict__ Q, short* __restrict__ K, short* __restrict__ Vt) {
    __shared__ __align__(16) short Al[128 * 32];
    __shared__ __align__(16) short Bl[128 * 32];
    const int mat = blockIdx.z;
    const short* B = mat == 0 ? Wq : (mat == 1 ? Wk : Wv);
    const int m0 = blockIdx.y * 128, n0 = blockIdx.x * 128;
    const int t = threadIdx.x;
    f32x4 acc[4][4] = {};
    gemm_mainloop(Xbf, B, Al, Bl, m0, n0, t, acc);
    const int wave = t >> 6, lane = t & 63;
    const int wm = (wave >> 1) * 64, wn = (wave & 1) * 64;
    const int l15 = lane & 15, lg = lane >> 4;
    if (mat < 2) {
        short* Out = mat == 0 ? Q : K;
        const float qs = 0.125f * 1.44269504088896f;  // 1/sqrt(dk) * log2(e)
#pragma unroll
        for (int m = 0; m < 4; ++m) {
#pragma unroll
            for (int n = 0; n < 4; ++n) {
                int col = n0 + wn + n * 16 + l15;
                int h = col >> 6, d = col & 63;
#pragma unroll
                for (int j = 0; j < 4; ++j) {
                    int srow = m0 + wm + m * 16 + lg * 4 + j;
                    float v = acc[m][n][j];
                    float other = __shfl_xor(v, 1);
                    float2 cs = rt[srow * 32 + (d >> 1)];
                    v = (d & 1) ? (other * cs.y + v * cs.x)
                                : (v * cs.x - other * cs.y);
                    if (mat == 0) v *= qs;
                    Out[(h * S_LEN + srow) * DKH + d] = f2bf(v);
                }
            }
        }
    } else {
        // V: write transposed (H, 64, S) directly
#pragma unroll
        for (int m = 0; m < 4; ++m)
#pragma unroll
            for (int n = 0; n < 4; ++n) {
                int col = n0 + wn + n * 16 + l15;
                int h = col >> 6, d = col & 63;
                int srow0 = m0 + wm + m * 16 + lg * 4;
                short4 b;
                b.x = f2bf(acc[m][n][0]); b.y = f2bf(acc[m][n][1]);
                b.z = f2bf(acc[m][n][2]); b.w = f2bf(acc[m][n][3]);
                *reinterpret_cast<short4*>(&Vt[(size_t)(h * DKH + d) * S_LEN + srow0]) = b;
            }
    }
}

// Output projection. grid = (6, 32)
__global__ __launch_bounds__(256) void gemm_out_k(const short* __restrict__ Ab,
                                                  const short* __restrict__ Wo,
                                                  float* __restrict__ out) {
    __shared__ __align__(16) short Al[128 * 32];
    __shared__ __align__(16) short Bl[128 * 32];
    const int m0 = blockIdx.y * 128, n0 = blockIdx.x * 128;
    const int t = threadIdx.x;
    f32x4 acc[4][4] = {};
    gemm_mainloop(Ab, Wo, Al, Bl, m0, n0, t, acc);
    const int wave = t >> 6, lane = t & 63;
    const int wm = (wave >> 1) * 64, wn = (wave & 1) * 64;
    const int l15 = lane & 15, lg = lane >> 4;
#pragma unroll
    for (int m = 0; m < 4; ++m)
#pragma unroll
        for (int n = 0; n < 4; ++n)
#pragma unroll
            for (int j = 0; j < 4; ++j) {
                int srow = m0 + wm + m * 16 + lg * 4 + j;
                int col = n0 + wn + n * 16 + l15;
                out[srow * DM + col] = acc[m][n][j];
            }
}

// ---------------------------------------------------------------- attention
// Barrier-free swapped-operand causal flash attention. grid = 64*12
// (heavy-first), 4 INDEPENDENT waves, 16 q-rows/wave, KV tile 64.
// K/V read DIRECTLY from global into registers (per-head K/V is L1/L2
// resident; cross-wave redundancy absorbed by L1). V(t) issued at tile
// top; K(t+1) prefetched into ping-ponged regs right after QK(t).
// Only LDS use: per-wave P^T repack (same-wave lgkm dep, no barrier).
__global__ __launch_bounds__(256) void attn_k(const short* __restrict__ Q,
                                              const short* __restrict__ K,
                                              const short* __restrict__ Vt,
                                              short* __restrict__ Aout) {
    const int bx = blockIdx.x;
    const int h = bx % NH;
    const int qb = (S_LEN / 64 - 1) - (bx / NH);    // heaviest blocks first
    const int t = threadIdx.x;
    const int wave = t >> 6, lane = t & 63;
    const int l15 = lane & 15, lg = lane >> 4;
    const int q0w = qb * 64 + wave * 16;

    __shared__ __align__(16) short Pl[4][16][76];
    __shared__ __align__(16) float Ol[4][16][68];

    const short* Kh = K + (size_t)h * S_LEN * DKH;
    const short* Vh = Vt + (size_t)h * DKH * S_LEN;

    short8 qf[2];
#pragma unroll
    for (int ks = 0; ks < 2; ++ks)
        qf[ks] = *reinterpret_cast<const short8*>(
            &Q[(h * S_LEN + q0w + l15) * DKH + ks * 32 + lg * 8]);

    f32x4 o[4] = {};
    float mrun = -1e30f, lpart = 0.f;
    const int nt = qb + 1;

    short8 kfA[2][4], kfB[2][4];
    // prologue: K tile 0 -> kfA
#pragma unroll
    for (int ks = 0; ks < 2; ++ks)
#pragma unroll
        for (int n = 0; n < 4; ++n)
            kfA[ks][n] = *reinterpret_cast<const short8*>(
                &Kh[(n * 16 + l15) * DKH + ks * 32 + lg * 8]);

    auto tile_body = [&](short8 (&KC)[2][4], short8 (&KN)[2][4], int tile) {
        const int kv0 = tile * 64;
        // ---- V(t) loads issued early; consumed by PV after softmax
        short8 vf[2][4];
#pragma unroll
        for (int ks = 0; ks < 2; ++ks)
#pragma unroll
            for (int n = 0; n < 4; ++n)
                vf[ks][n] = *reinterpret_cast<const short8*>(
                    &Vh[(n * 16 + l15) * S_LEN + kv0 + ks * 32 + lg * 8]);

        // ---- S^T = K Q^T (Q pre-scaled by 1/8*log2e)
        f32x4 s[4] = {};
        __builtin_amdgcn_s_setprio(1);
#pragma unroll
        for (int ks = 0; ks < 2; ++ks)
#pragma unroll
            for (int n = 0; n < 4; ++n)
                s[n] = MFMA16(KC[ks][n], qf[ks], s[n]);
        __builtin_amdgcn_s_setprio(0);

        // ---- prefetch K(t+1) into the other reg set (KC now dead)
        if (tile + 1 < nt) {
            const int kr = kv0 + 64;
#pragma unroll
            for (int ks = 0; ks < 2; ++ks)
#pragma unroll
                for (int n = 0; n < 4; ++n)
                    KN[ks][n] = *reinterpret_cast<const short8*>(
                        &Kh[(kr + n * 16 + l15) * DKH + ks * 32 + lg * 8]);
        }

        // ---- causal mask (diagonal tile only)
        if (tile == qb) {
            const int q = q0w + l15;
#pragma unroll
            for (int n = 0; n < 4; ++n)
#pragma unroll
                for (int j = 0; j < 4; ++j)
                    if (kv0 + n * 16 + lg * 4 + j > q) s[n][j] = -1e30f;
        }

        // ---- per-lane local max; defer path has NO cross-lane ops
        float mt = fmaxf(fmaxf(fmaxf(s[0][0], s[0][1]), fmaxf(s[0][2], s[0][3])),
                         fmaxf(fmaxf(s[1][0], s[1][1]), fmaxf(s[1][2], s[1][3])));
        mt = fmaxf(mt, fmaxf(fmaxf(fmaxf(s[2][0], s[2][1]), fmaxf(s[2][2], s[2][3])),
                             fmaxf(fmaxf(s[3][0], s[3][1]), fmaxf(s[3][2], s[3][3]))));

        if (__all(mt <= mrun + 8.f)) {
#pragma unroll
            for (int n = 0; n < 4; ++n)
#pragma unroll
                for (int j = 0; j < 4; ++j) {
                    float p = exp2f(s[n][j] - mrun);
                    s[n][j] = p;
                    lpart += p;
                }
        } else {
            float mm = fmaxf(mt, __shfl_xor(mt, 16));
            mm = fmaxf(mm, __shfl_xor(mm, 32));
            float mnew = fmaxf(mrun, mm);
            float alpha = exp2f(mrun - mnew);
            lpart *= alpha;
#pragma unroll
            for (int n = 0; n < 4; ++n)
#pragma unroll
                for (int j = 0; j < 4; ++j) {
                    float p = exp2f(s[n][j] - mnew);
                    s[n][j] = p;
                    lpart += p;
                }
#pragma unroll
            for (int n = 0; n < 4; ++n)
#pragma unroll
                for (int j = 0; j < 4; ++j) o[n][j] *= alpha;
            mrun = mnew;
        }

        // ---- P^T -> per-wave LDS (no barrier; same-wave RAW)
#pragma unroll
        for (int n = 0; n < 4; ++n) {
            unsigned p0, p1;
            asm("v_cvt_pk_bf16_f32 %0, %1, %2" : "=v"(p0) : "v"(s[n][0]), "v"(s[n][1]));
            asm("v_cvt_pk_bf16_f32 %0, %1, %2" : "=v"(p1) : "v"(s[n][2]), "v"(s[n][3]));
            uint2 w; w.x = p0; w.y = p1;
            *reinterpret_cast<uint2*>(&Pl[wave][l15][n * 16 + lg * 4]) = w;
        }

        // ---- O^T += V^T P^T
        __builtin_amdgcn_s_setprio(1);
#pragma unroll
        for (int ks = 0; ks < 2; ++ks) {
            short8 pa = *reinterpret_cast<const short8*>(
                &Pl[wave][l15][ks * 32 + lg * 8]);
#pragma unroll
            for (int n = 0; n < 4; ++n)
                o[n] = MFMA16(vf[ks][n], pa, o[n]);
        }
        __builtin_amdgcn_s_setprio(0);
    };

    int tile = 0;
    while (tile + 2 <= nt) {
        tile_body(kfA, kfB, tile);
        tile_body(kfB, kfA, tile + 1);
        tile += 2;
    }
    if (tile < nt) tile_body(kfA, kfB, tile);

    // ---- combine deferred per-lane sums (once)
    float lsum = lpart + __shfl_xor(lpart, 16);
    lsum += __shfl_xor(lsum, 32);
    float inv = 1.f / lsum;

    // ---- O^T -> per-wave LDS transpose -> coalesced store (no barrier)
#pragma unroll
    for (int n = 0; n < 4; ++n) {
        float4 w;
        w.x = o[n][0] * inv; w.y = o[n][1] * inv;
        w.z = o[n][2] * inv; w.w = o[n][3] * inv;
        *reinterpret_cast<float4*>(&Ol[wave][l15][n * 16 + lg * 4]) = w;
    }
#pragma unroll
    for (int kk = 0; kk < 4; ++kk) {
        int r = lane >> 2, c0 = (lane & 3) * 4 + kk * 16;
        float4 v = *reinterpret_cast<const float4*>(&Ol[wave][r][c0]);
        short4 b;
        b.x = f2bf(v.x); b.y = f2bf(v.y); b.z = f2bf(v.z); b.w = f2bf(v.w);
        *reinterpret_cast<short4*>(
            &Aout[(size_t)(q0w + r) * DM + h * DKH + c0]) = b;
    }
}

// ---------------------------------------------------------------- launcher
extern "C" void kernel_launch(void* const* d_in, const int* in_sizes, int n_in,
                              void* d_out, int out_size, void* d_ws, size_t ws_size,
                              hipStream_t stream) {
    const float* X  = (const float*)d_in[0];
    const int*   pos = (const int*)d_in[1];
    const float* Wq = (const float*)d_in[2];
    const float* Wk = (const float*)d_in[3];
    const float* Wv = (const float*)d_in[4];
    const float* Wo = (const float*)d_in[5];
    float* out = (float*)d_out;

    char* ws = (char*)d_ws;
    short* Xbf = (short*)ws;  ws += (size_t)S_LEN * DM * 2;
    short* Wqb = (short*)ws;  ws += (size_t)DM * DM * 2;
    short* Wkb = (short*)ws;  ws += (size_t)DM * DM * 2;
    short* Wvb = (short*)ws;  ws += (size_t)DM * DM * 2;
    short* Wob = (short*)ws;  ws += (size_t)DM * DM * 2;
    float2* rt = (float2*)ws; ws += (size_t)S_LEN * 32 * 8;
    short* Qb  = (short*)ws;  ws += (size_t)NH * S_LEN * DKH * 2;
    short* Kb  = (short*)ws;  ws += (size_t)NH * S_LEN * DKH * 2;
    short* Vtb = (short*)ws;  ws += (size_t)NH * S_LEN * DKH * 2;
    short* Ab  = (short*)ws;  ws += (size_t)S_LEN * DM * 2;

    to_bf16_k<<<(S_LEN * DM / 4 + 255) / 256, 256, 0, stream>>>(X, Xbf, S_LEN * DM);
    to_bf16_k<<<(DM * DM / 4 + 255) / 256, 256, 0, stream>>>(Wq, Wqb, DM * DM);
    to_bf16_k<<<(DM * DM / 4 + 255) / 256, 256, 0, stream>>>(Wk, Wkb, DM * DM);
    to_bf16_k<<<(DM * DM / 4 + 255) / 256, 256, 0, stream>>>(Wv, Wvb, DM * DM);
    to_bf16_k<<<(DM * DM / 4 + 255) / 256, 256, 0, stream>>>(Wo, Wob, DM * DM);
    rope_table_k<<<(S_LEN * 32 + 255) / 256, 256, 0, stream>>>(pos, rt);

    gemm_qkv_k<<<dim3(6, 32, 3), 256, 0, stream>>>(Xbf, Wqb, Wkb, Wvb, rt, Qb, Kb, Vtb);
    attn_k<<<dim3(64 * NH), 256, 0, stream>>>(Qb, Kb, Vtb, Ab);
    gemm_out_k<<<dim3(6, 32), 256, 0, stream>>>(Ab, Wob, out);
}

// Round 7
// 159.812 us; speedup vs baseline: 1.7035x; 1.7035x over previous
//
#include <hip/hip_runtime.h>
#include <hip/hip_bf16.h>

#define S_LEN 4096
#define DM    768
#define NH    12
#define DKH   64

typedef __attribute__((ext_vector_type(8))) short short8;
typedef __attribute__((ext_vector_type(4))) float f32x4;

__device__ __forceinline__ short f2bf(float f) {
    union { float f; unsigned u; } v; v.f = f;
    unsigned r = (v.u + 0x7FFFu + ((v.u >> 16) & 1u)) >> 16;
    return (short)r;
}

#define MFMA16(a, b, c) __builtin_amdgcn_mfma_f32_16x16x32_bf16((a), (b), (c), 0, 0, 0)

// ---------------------------------------------------------------- converts
__global__ __launch_bounds__(256) void to_bf16_k(const float* __restrict__ src,
                                                 short* __restrict__ dst, int n) {
    int i = (blockIdx.x * 256 + threadIdx.x) * 4;
    if (i >= n) return;
    float4 v = *reinterpret_cast<const float4*>(src + i);
    short4 o;
    o.x = f2bf(v.x); o.y = f2bf(v.y); o.z = f2bf(v.z); o.w = f2bf(v.w);
    *reinterpret_cast<short4*>(dst + i) = o;
}

__global__ __launch_bounds__(256) void rope_table_k(const int* __restrict__ pos,
                                                    float2* __restrict__ rt) {
    int idx = blockIdx.x * 256 + threadIdx.x;
    if (idx >= S_LEN * 32) return;
    int s = idx >> 5, i = idx & 31;
    int p = pos[s]; p = p < 0 ? 0 : (p > 4095 ? 4095 : p);
    double inv = pow(10000.0, -(double)i / 32.0);
    float ang = (float)((double)p * inv);
    rt[idx] = make_float2(cosf(ang), sinf(ang));
}

// ---------------------------------------------------------------- GEMM core
// m97 structure: 128x128 tile, BK=32, global_load_lds(16B) staging with
// XOR-chunk swizzle on the GLOBAL source (linear LDS dest, rule #21).
__device__ __forceinline__ void gemm_mainloop(const short* __restrict__ A,
                                              const short* __restrict__ B,
                                              short* Al, short* Bl,
                                              int m0, int n0, int t,
                                              f32x4 acc[4][4]) {
    const int wave = t >> 6, lane = t & 63;
    const int wm = (wave >> 1) * 64, wn = (wave & 1) * 64;
    const int l15 = lane & 15, lg = lane >> 4;
    const int srow = lane >> 2;
    const int gca = (lane & 3) ^ (srow & 3);
    const int c8a = lg ^ (l15 & 3);
    short* dstA0 = Al + (wave * 2 + 0) * 512 + lane * 8;
    short* dstA1 = Al + (wave * 2 + 1) * 512 + lane * 8;
    short* dstB0 = Bl + (wave * 2 + 0) * 512 + lane * 8;
    short* dstB1 = Bl + (wave * 2 + 1) * 512 + lane * 8;
    const int ra0 = (wave * 2 + 0) * 16 + srow;
    const int ra1 = (wave * 2 + 1) * 16 + srow;
    for (int k0 = 0; k0 < DM; k0 += 32) {
        __syncthreads();
        __builtin_amdgcn_global_load_lds(
            (const __attribute__((address_space(1))) void*)&A[(m0 + ra0) * DM + k0 + gca * 8],
            (__attribute__((address_space(3))) void*)dstA0, 16, 0, 0);
        __builtin_amdgcn_global_load_lds(
            (const __attribute__((address_space(1))) void*)&A[(m0 + ra1) * DM + k0 + gca * 8],
            (__attribute__((address_space(3))) void*)dstA1, 16, 0, 0);
        __builtin_amdgcn_global_load_lds(
            (const __attribute__((address_space(1))) void*)&B[(n0 + ra0) * DM + k0 + gca * 8],
            (__attribute__((address_space(3))) void*)dstB0, 16, 0, 0);
        __builtin_amdgcn_global_load_lds(
            (const __attribute__((address_space(1))) void*)&B[(n0 + ra1) * DM + k0 + gca * 8],
            (__attribute__((address_space(3))) void*)dstB1, 16, 0, 0);
        __syncthreads();
        short8 af[4], bf[4];
#pragma unroll
        for (int m = 0; m < 4; ++m)
            af[m] = *reinterpret_cast<const short8*>(Al + (wm + m * 16 + l15) * 32 + c8a * 8);
#pragma unroll
        for (int n = 0; n < 4; ++n)
            bf[n] = *reinterpret_cast<const short8*>(Bl + (wn + n * 16 + l15) * 32 + c8a * 8);
#pragma unroll
        for (int m = 0; m < 4; ++m)
#pragma unroll
            for (int n = 0; n < 4; ++n)
                acc[m][n] = MFMA16(af[m], bf[n], acc[m][n]);
    }
}

// QKV projection + fused RoPE (+ 1/8*log2e on Q) + fused V-transpose.
// grid = (6, 32, 3)
__global__ __launch_bounds__(256) void gemm_qkv_k(
    const short* __restrict__ Xbf, const short* __restrict__ Wq,
    const short* __restrict__ Wk, const short* __restrict__ Wv,
    const float2* __restrict__ rt,
    short* __restrict__ Q, short* __restrict__ K, short* __restrict__ Vt) {
    __shared__ __align__(16) short Al[128 * 32];
    __shared__ __align__(16) short Bl[128 * 32];
    const int mat = blockIdx.z;
    const short* B = mat == 0 ? Wq : (mat == 1 ? Wk : Wv);
    const int m0 = blockIdx.y * 128, n0 = blockIdx.x * 128;
    const int t = threadIdx.x;
    f32x4 acc[4][4] = {};
    gemm_mainloop(Xbf, B, Al, Bl, m0, n0, t, acc);
    const int wave = t >> 6, lane = t & 63;
    const int wm = (wave >> 1) * 64, wn = (wave & 1) * 64;
    const int l15 = lane & 15, lg = lane >> 4;
    if (mat < 2) {
        short* Out = mat == 0 ? Q : K;
        const float qs = 0.125f * 1.44269504088896f;  // 1/sqrt(dk) * log2(e)
#pragma unroll
        for (int m = 0; m < 4; ++m) {
#pragma unroll
            for (int n = 0; n < 4; ++n) {
                int col = n0 + wn + n * 16 + l15;
                int h = col >> 6, d = col & 63;
#pragma unroll
                for (int j = 0; j < 4; ++j) {
                    int srow = m0 + wm + m * 16 + lg * 4 + j;
                    float v = acc[m][n][j];
                    float other = __shfl_xor(v, 1);
                    float2 cs = rt[srow * 32 + (d >> 1)];
                    v = (d & 1) ? (other * cs.y + v * cs.x)
                                : (v * cs.x - other * cs.y);
                    if (mat == 0) v *= qs;
                    Out[(h * S_LEN + srow) * DKH + d] = f2bf(v);
                }
            }
        }
    } else {
        // V: write transposed (H, 64, S) directly
#pragma unroll
        for (int m = 0; m < 4; ++m)
#pragma unroll
            for (int n = 0; n < 4; ++n) {
                int col = n0 + wn + n * 16 + l15;
                int h = col >> 6, d = col & 63;
                int srow0 = m0 + wm + m * 16 + lg * 4;
                short4 b;
                b.x = f2bf(acc[m][n][0]); b.y = f2bf(acc[m][n][1]);
                b.z = f2bf(acc[m][n][2]); b.w = f2bf(acc[m][n][3]);
                *reinterpret_cast<short4*>(&Vt[(size_t)(h * DKH + d) * S_LEN + srow0]) = b;
            }
    }
}

// Output projection. grid = (6, 32)
__global__ __launch_bounds__(256) void gemm_out_k(const short* __restrict__ Ab,
                                                  const short* __restrict__ Wo,
                                                  float* __restrict__ out) {
    __shared__ __align__(16) short Al[128 * 32];
    __shared__ __align__(16) short Bl[128 * 32];
    const int m0 = blockIdx.y * 128, n0 = blockIdx.x * 128;
    const int t = threadIdx.x;
    f32x4 acc[4][4] = {};
    gemm_mainloop(Ab, Wo, Al, Bl, m0, n0, t, acc);
    const int wave = t >> 6, lane = t & 63;
    const int wm = (wave >> 1) * 64, wn = (wave & 1) * 64;
    const int l15 = lane & 15, lg = lane >> 4;
#pragma unroll
    for (int m = 0; m < 4; ++m)
#pragma unroll
        for (int n = 0; n < 4; ++n)
#pragma unroll
            for (int j = 0; j < 4; ++j) {
                int srow = m0 + wm + m * 16 + lg * 4 + j;
                int col = n0 + wn + n * 16 + l15;
                out[srow * DM + col] = acc[m][n][j];
            }
}

// ---------------------------------------------------------------- attention
__device__ __forceinline__ void stage64(const short* __restrict__ gRow0,
                                        int rowStride, short* lbuf,
                                        int wave, int lane) {
#pragma unroll
    for (int i = 0; i < 2; ++i) {
        int c = wave + i * 4;                     // 1KB chunk 0..7
        int row = c * 8 + (lane >> 3);            // tile row 0..63
        int gch = (lane & 7) ^ (lane >> 3);       // swizzled 16B chunk in row
        const short* src = gRow0 + (long)row * rowStride + gch * 8;
        short* dst = lbuf + c * 512 + lane * 8;   // linear: row*64 + chunk*8
        __builtin_amdgcn_global_load_lds(
            (const __attribute__((address_space(1))) void*)src,
            (__attribute__((address_space(3))) void*)dst, 16, 0, 0);
    }
}

// Swapped-operand causal flash attention with a COUNTED-COVERED pipeline:
// per tile, K/V(t+1) staged via global_load_lds BEFORE compute; the only
// wait is a vmcnt(0) AFTER compute (latency fully covered) + ONE raw
// s_barrier (no implicit drain). grid = 64*12 heavy-first, 4 waves,
// 16 q-rows/wave, KV tile 64, K/V double-buffered (42.5KB, 3 blocks/CU).
__global__ __launch_bounds__(256) void attn_k(const short* __restrict__ Q,
                                              const short* __restrict__ K,
                                              const short* __restrict__ Vt,
                                              short* __restrict__ Aout) {
    const int bx = blockIdx.x;
    const int h = bx % NH;
    const int qb = (S_LEN / 64 - 1) - (bx / NH);    // heaviest blocks first
    const int t = threadIdx.x;
    const int wave = t >> 6, lane = t & 63;
    const int l15 = lane & 15, lg = lane >> 4;
    const int q0w = qb * 64 + wave * 16;

    __shared__ __align__(16) short KVl[2][2][64 * 64];  // [buf][K|V]
    __shared__ __align__(16) short Pl[4][16][76];

    const short* Kh = K + (size_t)h * S_LEN * DKH;
    const short* Vh = Vt + (size_t)h * DKH * S_LEN;

    short8 qf[2];
#pragma unroll
    for (int ks = 0; ks < 2; ++ks)
        qf[ks] = *reinterpret_cast<const short8*>(
            &Q[(h * S_LEN + q0w + l15) * DKH + ks * 32 + lg * 8]);

    f32x4 o[4] = {};
    float mrun = -1e30f, lpart = 0.f;
    const int nt = qb + 1;

    // prologue: tile 0 into buf 0 (full drain once is fine)
    stage64(Kh, DKH, KVl[0][0], wave, lane);
    stage64(Vh, S_LEN, KVl[0][1], wave, lane);
    __syncthreads();

    for (int tile = 0; tile < nt; ++tile) {
        const int cur = tile & 1;
        // ---- issue next tile's staging FIRST (latency hides under compute)
        if (tile + 1 < nt) {
            stage64(Kh + (size_t)(tile + 1) * 64 * DKH, DKH, KVl[cur ^ 1][0], wave, lane);
            stage64(Vh + (tile + 1) * 64, S_LEN, KVl[cur ^ 1][1], wave, lane);
        }
        __builtin_amdgcn_sched_barrier(0);   // pin issue point
        const char* Kb = (const char*)KVl[cur][0];
        const char* Vb = (const char*)KVl[cur][1];

        // ---- S^T = K Q^T (Q pre-scaled by 1/8*log2e)
        f32x4 s[4] = {};
        __builtin_amdgcn_s_setprio(1);
#pragma unroll
        for (int ks = 0; ks < 2; ++ks)
#pragma unroll
            for (int n = 0; n < 4; ++n) {
                int r = n * 16 + l15;
                int c8 = (ks * 4 + lg) ^ (r & 7);
                short8 kf = *reinterpret_cast<const short8*>(Kb + r * 128 + c8 * 16);
                s[n] = MFMA16(kf, qf[ks], s[n]);
            }
        __builtin_amdgcn_s_setprio(0);

        // ---- causal mask (diagonal tile only)
        if (tile == qb) {
            const int q = q0w + l15;
#pragma unroll
            for (int n = 0; n < 4; ++n)
#pragma unroll
                for (int j = 0; j < 4; ++j)
                    if (tile * 64 + n * 16 + lg * 4 + j > q) s[n][j] = -1e30f;
        }

        // ---- per-lane local max; defer path has NO cross-lane ops
        float mt = fmaxf(fmaxf(fmaxf(s[0][0], s[0][1]), fmaxf(s[0][2], s[0][3])),
                         fmaxf(fmaxf(s[1][0], s[1][1]), fmaxf(s[1][2], s[1][3])));
        mt = fmaxf(mt, fmaxf(fmaxf(fmaxf(s[2][0], s[2][1]), fmaxf(s[2][2], s[2][3])),
                             fmaxf(fmaxf(s[3][0], s[3][1]), fmaxf(s[3][2], s[3][3]))));

        if (__all(mt <= mrun + 8.f)) {
#pragma unroll
            for (int n = 0; n < 4; ++n)
#pragma unroll
                for (int j = 0; j < 4; ++j) {
                    float p = exp2f(s[n][j] - mrun);
                    s[n][j] = p;
                    lpart += p;
                }
        } else {
            float mm = fmaxf(mt, __shfl_xor(mt, 16));
            mm = fmaxf(mm, __shfl_xor(mm, 32));
            float mnew = fmaxf(mrun, mm);
            float alpha = exp2f(mrun - mnew);
            lpart *= alpha;
#pragma unroll
            for (int n = 0; n < 4; ++n)
#pragma unroll
                for (int j = 0; j < 4; ++j) {
                    float p = exp2f(s[n][j] - mnew);
                    s[n][j] = p;
                    lpart += p;
                }
#pragma unroll
            for (int n = 0; n < 4; ++n)
#pragma unroll
                for (int j = 0; j < 4; ++j) o[n][j] *= alpha;
            mrun = mnew;
        }

        // ---- P^T -> per-wave LDS (same-wave RAW; no barrier needed)
#pragma unroll
        for (int n = 0; n < 4; ++n) {
            unsigned p0, p1;
            asm("v_cvt_pk_bf16_f32 %0, %1, %2" : "=v"(p0) : "v"(s[n][0]), "v"(s[n][1]));
            asm("v_cvt_pk_bf16_f32 %0, %1, %2" : "=v"(p1) : "v"(s[n][2]), "v"(s[n][3]));
            uint2 w; w.x = p0; w.y = p1;
            *reinterpret_cast<uint2*>(&Pl[wave][l15][n * 16 + lg * 4]) = w;
        }

        // ---- O^T += V^T P^T
        __builtin_amdgcn_s_setprio(1);
#pragma unroll
        for (int ks = 0; ks < 2; ++ks) {
            short8 pa = *reinterpret_cast<const short8*>(
                &Pl[wave][l15][ks * 32 + lg * 8]);
#pragma unroll
            for (int n = 0; n < 4; ++n) {
                int r = n * 16 + l15;
                int c8 = (ks * 4 + lg) ^ (r & 7);
                short8 vf = *reinterpret_cast<const short8*>(Vb + r * 128 + c8 * 16);
                o[n] = MFMA16(vf, pa, o[n]);
            }
        }
        __builtin_amdgcn_s_setprio(0);

        // ---- pipeline fence: vmcnt covered by the whole tile's compute;
        // ONE raw barrier (no drain) hands buffers over.
        asm volatile("s_waitcnt vmcnt(0)" ::: "memory");
        __builtin_amdgcn_sched_barrier(0);
        __builtin_amdgcn_s_barrier();
    }

    // ---- combine deferred per-lane sums (once)
    float lsum = lpart + __shfl_xor(lpart, 16);
    lsum += __shfl_xor(lsum, 32);
    float inv = 1.f / lsum;

    __syncthreads();   // safe LDS reuse for epilogue
    float* Ol = (float*)&KVl[0][0][0] + wave * (16 * 68);
#pragma unroll
    for (int n = 0; n < 4; ++n) {
        float4 w;
        w.x = o[n][0] * inv; w.y = o[n][1] * inv;
        w.z = o[n][2] * inv; w.w = o[n][3] * inv;
        *reinterpret_cast<float4*>(&Ol[l15 * 68 + n * 16 + lg * 4]) = w;
    }
#pragma unroll
    for (int kk = 0; kk < 4; ++kk) {
        int r = lane >> 2, c0 = (lane & 3) * 4 + kk * 16;
        float4 v = *reinterpret_cast<const float4*>(&Ol[r * 68 + c0]);
        short4 b;
        b.x = f2bf(v.x); b.y = f2bf(v.y); b.z = f2bf(v.z); b.w = f2bf(v.w);
        *reinterpret_cast<short4*>(
            &Aout[(size_t)(q0w + r) * DM + h * DKH + c0]) = b;
    }
}

// ---------------------------------------------------------------- launcher
extern "C" void kernel_launch(void* const* d_in, const int* in_sizes, int n_in,
                              void* d_out, int out_size, void* d_ws, size_t ws_size,
                              hipStream_t stream) {
    const float* X  = (const float*)d_in[0];
    const int*   pos = (const int*)d_in[1];
    const float* Wq = (const float*)d_in[2];
    const float* Wk = (const float*)d_in[3];
    const float* Wv = (const float*)d_in[4];
    const float* Wo = (const float*)d_in[5];
    float* out = (float*)d_out;

    char* ws = (char*)d_ws;
    short* Xbf = (short*)ws;  ws += (size_t)S_LEN * DM * 2;
    short* Wqb = (short*)ws;  ws += (size_t)DM * DM * 2;
    short* Wkb = (short*)ws;  ws += (size_t)DM * DM * 2;
    short* Wvb = (short*)ws;  ws += (size_t)DM * DM * 2;
    short* Wob = (short*)ws;  ws += (size_t)DM * DM * 2;
    float2* rt = (float2*)ws; ws += (size_t)S_LEN * 32 * 8;
    short* Qb  = (short*)ws;  ws += (size_t)NH * S_LEN * DKH * 2;
    short* Kb  = (short*)ws;  ws += (size_t)NH * S_LEN * DKH * 2;
    short* Vtb = (short*)ws;  ws += (size_t)NH * S_LEN * DKH * 2;
    short* Ab  = (short*)ws;  ws += (size_t)S_LEN * DM * 2;

    to_bf16_k<<<(S_LEN * DM / 4 + 255) / 256, 256, 0, stream>>>(X, Xbf, S_LEN * DM);
    to_bf16_k<<<(DM * DM / 4 + 255) / 256, 256, 0, stream>>>(Wq, Wqb, DM * DM);
    to_bf16_k<<<(DM * DM / 4 + 255) / 256, 256, 0, stream>>>(Wk, Wkb, DM * DM);
    to_bf16_k<<<(DM * DM / 4 + 255) / 256, 256, 0, stream>>>(Wv, Wvb, DM * DM);
    to_bf16_k<<<(DM * DM / 4 + 255) / 256, 256, 0, stream>>>(Wo, Wob, DM * DM);
    rope_table_k<<<(S_LEN * 32 + 255) / 256, 256, 0, stream>>>(pos, rt);

    gemm_qkv_k<<<dim3(6, 32, 3), 256, 0, stream>>>(Xbf, Wqb, Wkb, Wvb, rt, Qb, Kb, Vtb);
    attn_k<<<dim3(64 * NH), 256, 0, stream>>>(Qb, Kb, Vtb, Ab);
    gemm_out_k<<<dim3(6, 32), 256, 0, stream>>>(Ab, Wob, out);
}